// Round 8
// baseline (361.559 us; speedup 1.0000x reference)
//
#include <hip/hip_runtime.h>
#include <math.h>

// MoE FFN, routed (top-2 pair-grouped), round 8:
//   prep (1 fused kernel): router(f64)+xb, pack w1/w2 images, ltw transpose,
//                          slot-init
//   build_scatter (1 block): LDS hist -> tile meta -> LDS-atomic scatter
//   G1: 64x128 BK=128 (image out)  G2: 64x128 BK=128 (image A, row out, XCD=n)
//   G3: 128x128 BK=64 strided, split-K x2 (1024 blocks = 4/CU) + reduce_out
// Image swizzle: elem(r,k) at r*128 + (((k>>3)^(r&15))<<3 | (k&7)).

using short8  = __attribute__((ext_vector_type(8))) short;
using floatx4 = __attribute__((ext_vector_type(4))) float;
typedef unsigned short bf16_t;

#define TOK   8192
#define HDIM  1024
#define RDIM  256
#define FDIM  4096
#define NEXP  8
#define MAXTILES 96
#define MAXSLOTS 16384
#define IMG   16384

__device__ __forceinline__ bf16_t f2bf(float f) {
  union { float f; unsigned u; } a; a.f = f;
  unsigned u = a.u;
  return (bf16_t)((u + 0x7FFFu + ((u >> 16) & 1u)) >> 16);  // RNE
}

__device__ __forceinline__ float gelu_erf(float v) {
  return 0.5f * v * (1.0f + erff(v * 0.70710678118654752f));
}

__device__ __forceinline__ void gload16(const void* g, void* l) {
  __builtin_amdgcn_global_load_lds(
      (const __attribute__((address_space(1))) void*)g,
      (__attribute__((address_space(3))) void*)l, 16, 0, 0);
}

__device__ __forceinline__ int swz_off(int r, int kl) {
  return r * 128 + ((((kl >> 3) ^ (r & 15)) << 3) | (kl & 7));
}

// ---------------------------------------------------------------- prep

__device__ __forceinline__ void pack_tile_body(const float* __restrict__ src,
                                               size_t kStride,
                                               bf16_t* __restrict__ img,
                                               bf16_t* __restrict__ lim) {
  const int tid = threadIdx.x;
  const int rr = tid & 127, half = tid >> 7;
  for (int kl = half; kl < 128; kl += 2)
    lim[swz_off(rr, kl)] = f2bf(src[(size_t)kl * kStride + rr]);
  __syncthreads();
  const int4* s4 = (const int4*)lim;
  int4* d4 = (int4*)img;
#pragma unroll
  for (int i = 0; i < 8; i++) d4[tid + i * 256] = s4[tid + i * 256];
}

// blockIdx ranges: [0,2048) router ; [2048,2176) pack_w1 ; [2176,2688) pack_w2
//                  [2688,3712) ltw transpose ; [3712,3776) slot init
__global__ __launch_bounds__(256)
void prep(const float* __restrict__ x, const float* __restrict__ rw,
          const float* __restrict__ rb, const float* __restrict__ w1,
          const float* __restrict__ w2, const float* __restrict__ l2w,
          int* __restrict__ gid_tok, float2* __restrict__ tokscale,
          bf16_t* __restrict__ xb, bf16_t* __restrict__ w1p,
          bf16_t* __restrict__ w2p, bf16_t* __restrict__ ltw,
          int* __restrict__ tokslot, float2* __restrict__ slotsc) {
  __shared__ __align__(16) char smem[33280];
  const int b = blockIdx.x;
  const int t = threadIdx.x;

  if (b < 2048) {
    // ---- router: f64 logits (selection-safe) + xb emit
    const int token = b * 4 + (t >> 6);
    const int lane  = t & 63;
    const float* xr = x + (size_t)token * HDIM;
    bf16_t* xbr = xb + (size_t)token * HDIM;
    double acc[NEXP];
#pragma unroll
    for (int e = 0; e < NEXP; e++) acc[e] = 0.0;
    for (int h = lane; h < HDIM; h += 64) {
      const float xf = xr[h];
      xbr[h] = f2bf(xf);
      const double xv = (double)xf;
      const float* wr = rw + (size_t)h * NEXP;
#pragma unroll
      for (int e = 0; e < NEXP; e++) acc[e] += xv * (double)wr[e];
    }
#pragma unroll
    for (int off = 32; off > 0; off >>= 1) {
#pragma unroll
      for (int e = 0; e < NEXP; e++) acc[e] += __shfl_xor(acc[e], off, 64);
    }
    double lg[NEXP];
#pragma unroll
    for (int e = 0; e < NEXP; e++) lg[e] = acc[e] + (double)rb[e];
    double mx = lg[0];
#pragma unroll
    for (int e = 1; e < NEXP; e++) mx = fmax(mx, lg[e]);
    double p[NEXP]; double den = 0.0;
#pragma unroll
    for (int e = 0; e < NEXP; e++) { p[e] = exp(lg[e] - mx); den += p[e]; }
    int i1 = 0;
#pragma unroll
    for (int e = 1; e < NEXP; e++) if (lg[e] > lg[i1]) i1 = e;
    int i2 = (i1 == 0) ? 1 : 0;
#pragma unroll
    for (int e = 0; e < NEXP; e++)
      if (e != i1 && e != i2 && lg[e] > lg[i2]) i2 = e;
    if (lane == 0) {
      const int elo = min(i1, i2), ehi = max(i1, i2);
      gid_tok[token] = elo * 8 + ehi;
      tokscale[token] = make_float2((float)(p[elo] / den), (float)(p[ehi] / den));
    }
  } else if (b < 2176) {
    // ---- pack w1 -> w1p images [e][nc][kb]
    const int img = b - 2048;
    const int e = img >> 4, nc = (img >> 3) & 1, kb = img & 7;
    pack_tile_body(w1 + (size_t)e * 1024 * 256 + (size_t)kb * 128 * 256 + nc * 128,
                   256, w1p + (size_t)img * IMG, (bf16_t*)smem);
  } else if (b < 2688) {
    // ---- pack w2 -> w2p images [n][e][kb]
    const int img = b - 2176;
    const int n = img >> 4, e = (img >> 1) & 7, kb = img & 1;
    pack_tile_body(w2 + (size_t)e * 256 * 4096 + (size_t)kb * 128 * 4096 + n * 128,
                   4096, w2p + (size_t)img * IMG, (bf16_t*)smem);
  } else if (b < 3712) {
    // ---- lin2_w [F][H] -> ltw[h][f] row-major bf16, 64x64 tiles
    float* tile = (float*)smem;  // [64][65]
    const int bid = b - 2688;
    const int c0 = (bid & 15) * 64;   // h
    const int r0 = (bid >> 4) * 64;   // f
    const int tx = t & 63, ty = t >> 6;
#pragma unroll
    for (int i = 0; i < 64; i += 4)
      tile[(ty + i) * 65 + tx] = l2w[(size_t)(r0 + ty + i) * HDIM + (c0 + tx)];
    __syncthreads();
#pragma unroll
    for (int i = 0; i < 64; i += 4)
      ltw[(size_t)(c0 + ty + i) * FDIM + (r0 + tx)] = f2bf(tile[tx * 65 + ty + i]);
  } else {
    // ---- slot init
    const int i = (b - 3712) * 256 + t;
    tokslot[i] = -1;
    slotsc[i] = make_float2(0.f, 0.f);
  }
}

// ---------------------------------------------------------------- routing
// ctrl ints: [192] n_tiles, [256 + 3t ..] meta{gid, slot0, nrows}

__global__ void build_scatter(const int* __restrict__ gid_tok,
                              const float2* __restrict__ tokscale,
                              int* __restrict__ ctrl,
                              int* __restrict__ tok_of_slot,
                              float2* __restrict__ scale_of_slot) {
  __shared__ int hist[64], ntl[64], start[64], fill[64];
  const int t = threadIdx.x;
  if (t < 64) { hist[t] = 0; fill[t] = 0; }
  __syncthreads();
  for (int i = t; i < TOK; i += 256) atomicAdd(&hist[gid_tok[i]], 1);
  __syncthreads();
  if (t < 64) ntl[t] = (hist[t] + 127) >> 7;
  __syncthreads();
  if (t < 64) {
    int slot0 = 0, tile0 = 0;
    for (int g = 0; g < t; g++) { slot0 += ntl[g] << 7; tile0 += ntl[g]; }
    start[t] = slot0;
    const int nt = ntl[t], c = hist[t];
    for (int i = 0; i < nt; i++) {
      ctrl[256 + (tile0 + i) * 3 + 0] = t;
      ctrl[256 + (tile0 + i) * 3 + 1] = slot0 + i * 128;
      ctrl[256 + (tile0 + i) * 3 + 2] = min(128, c - i * 128);
    }
    if (t == 63) ctrl[192] = tile0 + nt;
  }
  __syncthreads();
  for (int i = t; i < TOK; i += 256) {
    const int g = gid_tok[i];
    const int pos = atomicAdd(&fill[g], 1);
    const int slot = start[g] + pos;
    tok_of_slot[slot] = i;
    scale_of_slot[slot] = tokscale[i];
  }
}

// ---------------------------------------------------------------- G1
// 64x128 tile, BK=128. b: low3 = b&7 -> n = low3&3, mh = low3>>2 ; tile = b>>3.
// (XCD = b%8 pinned to (n,mh): per-XCD w1p working set L2-resident.)
__global__ __launch_bounds__(256)
void gemm_g1(const bf16_t* __restrict__ xb, const bf16_t* __restrict__ w1p,
             bf16_t* __restrict__ Tp, const int* __restrict__ ctrl,
             const int* __restrict__ tok_of_slot,
             const float2* __restrict__ scale_of_slot) {
  const int b = blockIdx.x;
  const int n = b & 3, mh = (b >> 2) & 1, tile = b >> 3;
  if (tile >= ctrl[192]) return;
  const int nrows = ctrl[256 + tile * 3 + 2];
  if (mh && nrows <= 64) return;
  __shared__ bf16_t As[64 * 128];
  __shared__ bf16_t Bs[128 * 128];
  const int gid   = ctrl[256 + tile * 3];
  const int slot0 = ctrl[256 + tile * 3 + 1];
  const int e = (n < 2) ? (gid >> 3) : (gid & 7);
  const int nc = n & 1;
  const int tid = threadIdx.x, lane = tid & 63, w = tid >> 6;
  const int wm = (w & 1) * 32, wn = (w >> 1) * 64;
  const int l16 = lane & 15, quad = lane >> 4;

  floatx4 acc[2][4];
  const floatx4 zero = {0.f, 0.f, 0.f, 0.f};
#pragma unroll
  for (int i = 0; i < 2; i++)
#pragma unroll
    for (int j = 0; j < 4; j++) acc[i][j] = zero;

  int toks[4];
  int rowAs[4];
#pragma unroll
  for (int i = 0; i < 4; i++) {
    rowAs[i] = w * 16 + i * 4 + (lane >> 4);
    int tk = tok_of_slot[slot0 + mh * 64 + rowAs[i]];
    toks[i] = (tk < 0) ? 0 : tk;
  }
  const bf16_t* bimg = w1p + (size_t)(e * 16 + nc * 8) * IMG;
  bf16_t* lA = As + w * 2048;
  bf16_t* lB = Bs + w * 4096;

  for (int kb = 0; kb < 8; kb++) {
    __syncthreads();
#pragma unroll
    for (int i = 0; i < 4; i++) {
      const int gq = (lane & 15) ^ (rowAs[i] & 15);
      gload16(xb + (size_t)toks[i] * HDIM + kb * 128 + gq * 8, lA + i * 512);
    }
#pragma unroll
    for (int i = 0; i < 8; i++)
      gload16(bimg + (size_t)kb * IMG + w * 4096 + i * 512 + lane * 8, lB + i * 512);
    __syncthreads();
#pragma unroll
    for (int s = 0; s < 4; s++) {
      const int pg = ((s * 4 + quad) ^ l16) << 3;
      short8 af[2], bfr[4];
#pragma unroll
      for (int i = 0; i < 2; i++)
        af[i] = *(const short8*)&As[(wm + i * 16 + l16) * 128 + pg];
#pragma unroll
      for (int i = 0; i < 4; i++)
        bfr[i] = *(const short8*)&Bs[(wn + i * 16 + l16) * 128 + pg];
#pragma unroll
      for (int mi = 0; mi < 2; mi++)
#pragma unroll
        for (int ni = 0; ni < 4; ni++)
          acc[mi][ni] = __builtin_amdgcn_mfma_f32_16x16x32_bf16(
              af[mi], bfr[ni], acc[mi][ni], 0, 0, 0);
    }
  }

  __syncthreads();
#pragma unroll
  for (int mi = 0; mi < 2; mi++) {
#pragma unroll
    for (int r = 0; r < 4; r++) {
      const int rloc = wm + mi * 16 + quad * 4 + r;
      const float2 sc = scale_of_slot[slot0 + mh * 64 + rloc];
      const float s = (n < 2) ? sc.x : sc.y;
#pragma unroll
      for (int ni = 0; ni < 4; ni++) {
        const int c = wn + ni * 16 + l16;
        As[swz_off(rloc, c)] = f2bf(acc[mi][ni][r] * s);
      }
    }
  }
  __syncthreads();
  bf16_t* img = Tp + (size_t)(tile * 4 + n) * IMG + mh * 64 * 128;
  const int4* s4 = (const int4*)As;
  int4* d4 = (int4*)img;
#pragma unroll
  for (int j = 0; j < 4; j++) d4[tid + j * 256] = s4[tid + j * 256];
}

// ---------------------------------------------------------------- G2
// 64x128 tile, BK=128. XCD pinned by n-group: xcd = b&7 = n>>2 ->
// per-XCD w2p working set = 2 MB (L2-resident across all tiles).
// decode: n = (b&7)*4 + ((b>>3)&3) ; mh = (b>>5)&1 ; tile = b>>6.
__global__ __launch_bounds__(256)
void gemm_g2(const bf16_t* __restrict__ Tp, const bf16_t* __restrict__ w2p,
             bf16_t* __restrict__ Hb, const int* __restrict__ ctrl,
             const int* __restrict__ tok_of_slot) {
  const int b = blockIdx.x;
  const int n = (b & 7) * 4 + ((b >> 3) & 3);
  const int mh = (b >> 5) & 1, tile = b >> 6;
  if (tile >= ctrl[192]) return;
  const int nrows = ctrl[256 + tile * 3 + 2];
  if (mh && nrows <= 64) return;
  __shared__ bf16_t As[64 * 128];
  __shared__ bf16_t Bs[128 * 128];
  const int gid   = ctrl[256 + tile * 3];
  const int slot0 = ctrl[256 + tile * 3 + 1];
  const int elo = gid >> 3, ehi = gid & 7;
  const int tid = threadIdx.x, lane = tid & 63, w = tid >> 6;
  const int wm = (w & 1) * 32, wn = (w >> 1) * 64;
  const int l16 = lane & 15, quad = lane >> 4;

  floatx4 acc[2][4];
  const floatx4 zero = {0.f, 0.f, 0.f, 0.f};
#pragma unroll
  for (int i = 0; i < 2; i++)
#pragma unroll
    for (int j = 0; j < 4; j++) acc[i][j] = zero;

  const bf16_t* aimg = Tp + (size_t)tile * 4 * IMG + mh * 64 * 128;
  bf16_t* lA = As + w * 2048;
  bf16_t* lB = Bs + w * 4096;

#pragma unroll
  for (int t = 0; t < 4; t++) {
    const int e = (t < 2) ? elo : ehi;
    const bf16_t* bimg = w2p + (size_t)(n * 16 + e * 2 + (t & 1)) * IMG;
    __syncthreads();
#pragma unroll
    for (int i = 0; i < 4; i++)
      gload16(aimg + (size_t)t * IMG + w * 2048 + i * 512 + lane * 8, lA + i * 512);
#pragma unroll
    for (int i = 0; i < 8; i++)
      gload16(bimg + w * 4096 + i * 512 + lane * 8, lB + i * 512);
    __syncthreads();
#pragma unroll
    for (int s = 0; s < 4; s++) {
      const int pg = ((s * 4 + quad) ^ l16) << 3;
      short8 af[2], bfr[4];
#pragma unroll
      for (int i = 0; i < 2; i++)
        af[i] = *(const short8*)&As[(wm + i * 16 + l16) * 128 + pg];
#pragma unroll
      for (int i = 0; i < 4; i++)
        bfr[i] = *(const short8*)&Bs[(wn + i * 16 + l16) * 128 + pg];
#pragma unroll
      for (int mi = 0; mi < 2; mi++)
#pragma unroll
        for (int ni = 0; ni < 4; ni++)
          acc[mi][ni] = __builtin_amdgcn_mfma_f32_16x16x32_bf16(
              af[mi], bfr[ni], acc[mi][ni], 0, 0, 0);
    }
  }

  // epilogue: gelu -> Bs row-major [64][128] -> coalesced token-row bursts
  __syncthreads();
#pragma unroll
  for (int mi = 0; mi < 2; mi++) {
#pragma unroll
    for (int r = 0; r < 4; r++) {
      const int rloc = wm + mi * 16 + quad * 4 + r;
#pragma unroll
      for (int ni = 0; ni < 4; ni++) {
        const int c = wn + ni * 16 + l16;
        Bs[rloc * 128 + c] = f2bf(gelu_erf(acc[mi][ni][r]));
      }
    }
  }
  __syncthreads();
  const int4* s4 = (const int4*)Bs;
#pragma unroll
  for (int j = 0; j < 4; j++) {
    const int chunk = tid + j * 256;
    const int row = chunk >> 4, off = chunk & 15;
    const int tok = tok_of_slot[slot0 + mh * 64 + row];
    if (tok >= 0)
      *(int4*)(Hb + (size_t)tok * FDIM + n * 128 + off * 8) = s4[chunk];
  }
}

// ---------------------------------------------------------------- G3
// 128x128 BK=64 strided, split-K x2 -> 1024 blocks (4 blocks/CU).
// b: xcd = b&7 ; r = b>>3 ; msub = r&7 ; n = (r>>3)&7 ; kb = r>>6.
// kb=0 -> partial to p0 ; kb=1 -> partial to out. reduce_out sums + bias.
__global__ __launch_bounds__(256)
void gemm_g3(const bf16_t* __restrict__ Hb, const bf16_t* __restrict__ ltw,
             float* __restrict__ out, float* __restrict__ p0) {
  __shared__ bf16_t As[128 * 64];
  __shared__ bf16_t Bs[128 * 64];
  const int b = blockIdx.x;
  const int r0 = b >> 3;
  const int m0 = ((b & 7) * 8 + (r0 & 7)) * 128;
  const int n0 = ((r0 >> 3) & 7) * 128;
  const int kb = r0 >> 6;
  const int tid = threadIdx.x, lane = tid & 63, w = tid >> 6;
  const int wm = (w >> 1) * 64, wn = (w & 1) * 64;
  const int l16 = lane & 15, quad = lane >> 4;
  const int rl = lane >> 3, gg = lane & 7;
  const int gf = (gg ^ rl) * 8;

  floatx4 acc[4][4];
  const floatx4 zero = {0.f, 0.f, 0.f, 0.f};
#pragma unroll
  for (int i = 0; i < 4; i++)
#pragma unroll
    for (int j = 0; j < 4; j++) acc[i][j] = zero;

  const bf16_t* ga[4];
  const bf16_t* gb[4];
#pragma unroll
  for (int c = 0; c < 4; c++) {
    ga[c] = Hb  + (size_t)(m0 + w * 32 + c * 8 + rl) * FDIM + kb * 2048 + gf;
    gb[c] = ltw + (size_t)(n0 + w * 32 + c * 8 + rl) * FDIM + kb * 2048 + gf;
  }
  bf16_t* lA = &As[w * 32 * 64];
  bf16_t* lB = &Bs[w * 32 * 64];

  for (int k0 = 0; k0 < 2048; k0 += 64) {
    __syncthreads();
#pragma unroll
    for (int c = 0; c < 4; c++) { gload16(ga[c], lA + c * 512); ga[c] += 64; }
#pragma unroll
    for (int c = 0; c < 4; c++) { gload16(gb[c], lB + c * 512); gb[c] += 64; }
    __syncthreads();
#pragma unroll
    for (int s = 0; s < 2; s++) {
      const int pg = ((s * 4 + quad) ^ (l16 & 7)) * 8;
      short8 af[4], bfr[4];
#pragma unroll
      for (int i = 0; i < 4; i++)
        af[i] = *(const short8*)&As[(wm + i * 16 + l16) * 64 + pg];
#pragma unroll
      for (int i = 0; i < 4; i++)
        bfr[i] = *(const short8*)&Bs[(wn + i * 16 + l16) * 64 + pg];
#pragma unroll
      for (int mi = 0; mi < 4; mi++)
#pragma unroll
        for (int ni = 0; ni < 4; ni++)
          acc[mi][ni] = __builtin_amdgcn_mfma_f32_16x16x32_bf16(
              af[mi], bfr[ni], acc[mi][ni], 0, 0, 0);
    }
  }

  float* dst = kb ? out : p0;
#pragma unroll
  for (int mi = 0; mi < 4; mi++) {
#pragma unroll
    for (int ni = 0; ni < 4; ni++) {
      const int row = m0 + wm + mi * 16 + quad * 4;
      const int col = n0 + wn + ni * 16 + l16;
#pragma unroll
      for (int r = 0; r < 4; r++)
        dst[(size_t)(row + r) * HDIM + col] = acc[mi][ni][r];
    }
  }
}

__global__ void reduce_out(float* __restrict__ out, const float* __restrict__ p0,
                           const float* __restrict__ bias) {
  const int i4 = blockIdx.x * 256 + threadIdx.x;  // float4 index
  float4 a = ((const float4*)out)[i4];
  float4 p = ((const float4*)p0)[i4];
  float4 bb = ((const float4*)bias)[i4 & 255];    // HDIM/4 = 256
  a.x += p.x + bb.x;
  a.y += p.y + bb.y;
  a.z += p.z + bb.z;
  a.w += p.w + bb.w;
  ((float4*)out)[i4] = a;
}

// ---------------------------------------------------------------- launch

extern "C" void kernel_launch(void* const* d_in, const int* in_sizes, int n_in,
                              void* d_out, int out_size, void* d_ws, size_t ws_size,
                              hipStream_t stream) {
  const float* x   = (const float*)d_in[0];
  const float* rw  = (const float*)d_in[1];
  const float* rb  = (const float*)d_in[2];
  const float* w1  = (const float*)d_in[3];
  const float* w2  = (const float*)d_in[4];
  const float* l2w = (const float*)d_in[5];
  const float* l2b = (const float*)d_in[6];

  char* ws = (char*)d_ws;
  int*    ctrl     = (int*)   (ws + 0);
  int*    gid_tok  = (int*)   (ws + 4096);
  float2* tokscale = (float2*)(ws + 36864);
  int*    tokslot  = (int*)   (ws + 102400);
  float2* slotsc   = (float2*)(ws + 167936);
  bf16_t* xb  = (bf16_t*)(ws + 1048576);        // 16.78 MB  (dead after G1/G2)
  bf16_t* w1p = (bf16_t*)(ws + 17825792);       //  4.19 MB  (dead after G1)
  bf16_t* w2p = (bf16_t*)(ws + 22020096);       // 16.78 MB  (dead after G2)
  bf16_t* ltw = (bf16_t*)(ws + 38797312);       //  8.39 MB  (alive thru G3)
  bf16_t* Tp  = (bf16_t*)(ws + 47185920);       // 12.58 MB  (dead after G2)
  bf16_t* Hb  = (bf16_t*)(ws + 59768832);       // 67.11 MB  (alive thru G3)
  float*  p0  = (float*) (ws + 1048576);        // 33.55 MB  (overlays xb/w1p/w2p
                                                //  region, all dead at G3 time)

  prep<<<3776, 256, 0, stream>>>(x, rw, rb, w1, w2, l2w,
                                 gid_tok, tokscale, xb, w1p, w2p, ltw,
                                 tokslot, slotsc);
  build_scatter<<<1, 256, 0, stream>>>(gid_tok, tokscale, ctrl, tokslot, slotsc);

  gemm_g1<<<8 * MAXTILES, 256, 0, stream>>>(xb, w1p, Tp, ctrl, tokslot, slotsc);
  gemm_g2<<<64 * MAXTILES, 256, 0, stream>>>(Tp, w2p, Hb, ctrl, tokslot);
  gemm_g3<<<1024, 256, 0, stream>>>(Hb, ltw, (float*)d_out, p0);
  reduce_out<<<TOK * HDIM / 1024, 256, 0, stream>>>((float*)d_out, p0, l2b);
}